// Round 11
// baseline (221.575 us; speedup 1.0000x reference)
//
#include <hip/hip_runtime.h>
#include <hip/hip_bf16.h>

#define SEQL 2048
#define DIMN 2048
#define NH 16
#define NKV 8
#define HD 128
#define NB 2

typedef float f32v4 __attribute__((ext_vector_type(4)));
typedef float f32v16 __attribute__((ext_vector_type(16)));
typedef __bf16 bfv8 __attribute__((ext_vector_type(8)));
typedef short s16v8 __attribute__((ext_vector_type(8)));
typedef unsigned short u16v4 __attribute__((ext_vector_type(4)));
typedef unsigned int u32v4 __attribute__((ext_vector_type(4)));
typedef int i32v2 __attribute__((ext_vector_type(2)));

__device__ inline unsigned short f2bf(float f){
  union { float f; unsigned u; } v; v.f = f;
  unsigned r = (v.u + 0x7fffu + ((v.u >> 16) & 1u)) >> 16;
  return (unsigned short)r;
}
__device__ inline float bf2f(unsigned short u){
  union { unsigned u; float f; } v; v.u = ((unsigned)u) << 16;
  return v.f;
}
__device__ inline f32v4 mfma16(bfv8 a, bfv8 b, f32v4 c){
  return __builtin_amdgcn_mfma_f32_16x16x32_bf16(a, b, c, 0, 0, 0);
}
__device__ inline f32v16 mfma32(bfv8 a, bfv8 b, f32v16 c){
  return __builtin_amdgcn_mfma_f32_32x32x16_bf16(a, b, c, 0, 0, 0);
}
__device__ inline bfv8 ld8(const unsigned short* p){
  s16v8 v = *reinterpret_cast<const s16v8*>(p);
  return __builtin_bit_cast(bfv8, v);
}
__device__ inline void gload16(const void* g, void* l){
  __builtin_amdgcn_global_load_lds(
      (const __attribute__((address_space(1))) unsigned int*)g,
      (__attribute__((address_space(3))) unsigned int*)l, 16, 0, 0);
}

// ---- fused fp32 -> bf16 convert for all 5 inputs (one dispatch) ----
__global__ __launch_bounds__(256) void cvtall(const float* __restrict__ x,
                                              const float* __restrict__ wq,
                                              const float* __restrict__ wk,
                                              const float* __restrict__ wv,
                                              const float* __restrict__ wo,
                                              unsigned short* __restrict__ xb,
                                              unsigned short* __restrict__ wqkvb,
                                              unsigned short* __restrict__ wob){
  const int bid = blockIdx.x;
  const float* src; unsigned short* dst; int off;
  if (bid < 8192)       { src = x;  dst = xb;              off = bid; }
  else if (bid < 12288) { src = wq; dst = wqkvb;           off = bid - 8192; }
  else if (bid < 14336) { src = wk; dst = wqkvb + 4194304; off = bid - 12288; }
  else if (bid < 16384) { src = wv; dst = wqkvb + 6291456; off = bid - 14336; }
  else                  { src = wo; dst = wob;             off = bid - 16384; }
  const int i = off * 256 + threadIdx.x;
  const float4 v = reinterpret_cast<const float4*>(src)[i];
  u16v4 w; w[0] = f2bf(v.x); w[1] = f2bf(v.y); w[2] = f2bf(v.z); w[3] = f2bf(v.w);
  reinterpret_cast<u16v4*>(dst)[i] = w;
}

// ---- deep-pipelined 256x256 GEMM: C = A * B^T, bf16 out (proven round-7) ----
__global__ __launch_bounds__(512, 2) void gemm3(const unsigned short* __restrict__ A,
                                                const unsigned short* __restrict__ B,
                                                unsigned short* __restrict__ Cp,
                                                int M, int N, int K){
  __shared__ unsigned short lds[65536];   // 4 slots x 16384 elems = 128 KB
  const int tid = threadIdx.x;
  const int lane = tid & 63, w = tid >> 6;
  const int wm = w >> 2, wn = w & 3;
  const int nbx = N >> 8;
  const int nwg = gridDim.x;
  const int cpx = nwg >> 3;
  const int id = blockIdx.x;
  const int swz = (id & 7) * cpx + (id >> 3);   // XCD-affine (nwg % 8 == 0)
  const int bm = (swz / nbx) * 256, bn = (swz % nbx) * 256;
  const int l15 = lane & 15, lg = lane >> 4;
  const int srow = w * 16 + (lane >> 2);
  const int cbg = ((lane & 3) ^ ((lane >> 3) & 3)) * 8;
  const int cbA = (lg ^ ((l15 >> 1) & 3)) * 8;

#define STAGE_A(T) { \
    const int kt_ = (T) * 32; \
    const int sl_ = ((T) & 3) * 16384; \
    const unsigned short* ga_ = &A[(size_t)(bm + srow) * K + kt_ + cbg]; \
    gload16(ga_,                    &lds[sl_ + w * 512]); \
    gload16(ga_ + (size_t)128 * K,  &lds[sl_ + 4096 + w * 512]); \
  }
#define STAGE_B(T) { \
    const int kt_ = (T) * 32; \
    const int sl_ = ((T) & 3) * 16384; \
    const unsigned short* gb_ = &B[(size_t)(bn + srow) * K + kt_ + cbg]; \
    gload16(gb_,                    &lds[sl_ + 8192 + w * 512]); \
    gload16(gb_ + (size_t)128 * K,  &lds[sl_ + 12288 + w * 512]); \
  }

  STAGE_A(0) STAGE_B(0) STAGE_A(1) STAGE_B(1) STAGE_A(2) STAGE_B(2)
  asm volatile("s_waitcnt vmcnt(8)" ::: "memory");
  __builtin_amdgcn_s_barrier();

  f32v4 acc[8][4] = {};
  const int nt = K >> 5;
  for (int t = 0; t < nt; ++t){
    const bool st = (t + 3 < nt);
    const int sl = (t & 3) * 16384;
    bfv8 af[8], bfr[4];
    #pragma unroll
    for (int j = 0; j < 4; ++j)
      bfr[j] = ld8(&lds[sl + 8192 + (wn * 64 + j * 16 + l15) * 32 + cbA]);
    #pragma unroll
    for (int i = 0; i < 4; ++i)
      af[i] = ld8(&lds[sl + (wm * 128 + i * 16 + l15) * 32 + cbA]);
    if (st) STAGE_A(t + 3)
    __builtin_amdgcn_s_barrier();
    __builtin_amdgcn_s_setprio(1);
    #pragma unroll
    for (int i = 0; i < 4; ++i)
      #pragma unroll
      for (int j = 0; j < 4; ++j)
        acc[i][j] = mfma16(af[i], bfr[j], acc[i][j]);
    __builtin_amdgcn_s_setprio(0);
    #pragma unroll
    for (int i = 4; i < 8; ++i)
      af[i] = ld8(&lds[sl + (wm * 128 + i * 16 + l15) * 32 + cbA]);
    if (st) STAGE_B(t + 3)
    __builtin_amdgcn_s_setprio(1);
    #pragma unroll
    for (int i = 4; i < 8; ++i)
      #pragma unroll
      for (int j = 0; j < 4; ++j)
        acc[i][j] = mfma16(af[i], bfr[j], acc[i][j]);
    __builtin_amdgcn_s_setprio(0);
    if (st)                asm volatile("s_waitcnt vmcnt(8)" ::: "memory");
    else if (t == nt - 3)  asm volatile("s_waitcnt vmcnt(4)" ::: "memory");
    else                   asm volatile("s_waitcnt vmcnt(0)" ::: "memory");
    __builtin_amdgcn_s_barrier();
  }
#undef STAGE_A
#undef STAGE_B

  #pragma unroll
  for (int i = 0; i < 8; ++i){
    #pragma unroll
    for (int j = 0; j < 4; ++j){
      const int gr = bm + wm * 128 + i * 16 + lg * 4;
      const int gc = bn + wn * 64 + j * 16 + l15;
      #pragma unroll
      for (int r = 0; r < 4; ++r)
        Cp[(size_t)(gr + r) * N + gc] = f2bf(acc[i][j][r]);
    }
  }
}

// ---- deep-pipelined 256x128 GEMM: C = A * B^T, fp32 out (WO projection) ----
__global__ __launch_bounds__(512, 2) void gemm3n(const unsigned short* __restrict__ A,
                                                 const unsigned short* __restrict__ B,
                                                 float* __restrict__ Cp,
                                                 int M, int N, int K){
  __shared__ unsigned short lds[49152];   // 4 slots x 12288 elems = 96 KB
  const int tid = threadIdx.x;
  const int lane = tid & 63, w = tid >> 6;
  const int wm = w >> 1, wn = w & 1;
  const int nbx = N >> 7;
  const int nwg = gridDim.x;
  const int cpx = nwg >> 3;
  const int id = blockIdx.x;
  const int swz = (id & 7) * cpx + (id >> 3);
  const int bm = (swz / nbx) * 256, bn = (swz % nbx) * 128;
  const int l15 = lane & 15, lg = lane >> 4;
  const int srow = tid >> 2;                       // 0..127
  const int cbg = ((tid & 3) ^ ((tid >> 3) & 3)) * 8;
  const int cbA = (lg ^ ((l15 >> 1) & 3)) * 8;

#define STAGEN(T) { \
    const int kt_ = (T) * 32; \
    const int sl_ = ((T) & 3) * 12288; \
    const unsigned short* ga_ = &A[(size_t)(bm + srow) * K + kt_ + cbg]; \
    gload16(ga_,                    &lds[sl_ + w * 512]); \
    gload16(ga_ + (size_t)128 * K,  &lds[sl_ + 4096 + w * 512]); \
    const unsigned short* gb_ = &B[(size_t)(bn + srow) * K + kt_ + cbg]; \
    gload16(gb_,                    &lds[sl_ + 8192 + w * 512]); \
  }

  STAGEN(0) STAGEN(1) STAGEN(2)
  asm volatile("s_waitcnt vmcnt(6)" ::: "memory");
  __builtin_amdgcn_s_barrier();

  f32v4 acc[4][4] = {};
  const int nt = K >> 5;
  for (int t = 0; t < nt; ++t){
    const bool st = (t + 3 < nt);
    if (st) STAGEN(t + 3)
    const int sl = (t & 3) * 12288;
    bfv8 af[4], bfr[4];
    #pragma unroll
    for (int i = 0; i < 4; ++i)
      af[i] = ld8(&lds[sl + (wm * 64 + i * 16 + l15) * 32 + cbA]);
    #pragma unroll
    for (int j = 0; j < 4; ++j)
      bfr[j] = ld8(&lds[sl + 8192 + (wn * 64 + j * 16 + l15) * 32 + cbA]);
    __builtin_amdgcn_s_setprio(1);
    #pragma unroll
    for (int i = 0; i < 4; ++i)
      #pragma unroll
      for (int j = 0; j < 4; ++j)
        acc[i][j] = mfma16(af[i], bfr[j], acc[i][j]);
    __builtin_amdgcn_s_setprio(0);
    if (st)                asm volatile("s_waitcnt vmcnt(6)" ::: "memory");
    else if (t == nt - 3)  asm volatile("s_waitcnt vmcnt(3)" ::: "memory");
    else                   asm volatile("s_waitcnt vmcnt(0)" ::: "memory");
    __builtin_amdgcn_s_barrier();
  }
#undef STAGEN

  #pragma unroll
  for (int i = 0; i < 4; ++i){
    #pragma unroll
    for (int j = 0; j < 4; ++j){
      const int gr = bm + wm * 64 + i * 16 + lg * 4;
      const int gc = bn + wn * 64 + j * 16 + l15;
      #pragma unroll
      for (int r = 0; r < 4; ++r)
        Cp[(size_t)(gr + r) * N + gc] = acc[i][j][r];
    }
  }
}

// ---- RoPE in-place on bf16 [rows][stride], rope'd cols 0..ncols-1, scaled ----
__global__ __launch_bounds__(256) void ropek(unsigned short* __restrict__ T,
                                             const float* __restrict__ fc,
                                             const float* __restrict__ fs, int ncols,
                                             int stride, float scale){
  int p = blockIdx.x * 256 + threadIdx.x;
  int half = ncols >> 1;
  int row = p / half;
  int pc = p - row * half;
  int h = pc >> 6, i = pc & 63;
  int s = row & (SEQL - 1);
  size_t idx = (size_t)row * stride + h * HD + 2 * i;
  float r = bf2f(T[idx]), im = bf2f(T[idx + 1]);
  float c = fc[s * 64 + i], sn = fs[s * 64 + i];
  T[idx]     = f2bf((r * c - im * sn) * scale);
  T[idx + 1] = f2bf((r * sn + im * c) * scale);
}

// ---- K swizzle + fused RoPE: QKVb fused [4096][4096] (K at col 2048) -> Kf ----
__global__ __launch_bounds__(256) void kswz(const unsigned short* __restrict__ QKVb,
                                            const float* __restrict__ fc,
                                            const float* __restrict__ fs,
                                            unsigned short* __restrict__ Kf){
  __shared__ unsigned short Ks[32][132];
  const int bk = blockIdx.y, kv32 = blockIdx.x;
  const int b = bk >> 3, kvh = bk & 7;
  const int t = threadIdx.x;
  const int r = t >> 3, cc = (t & 7) * 16;
  const int s = kv32 * 32 + r;
  const unsigned short* src = QKVb + (size_t)(b * SEQL + s) * 4096 + 2048 + kvh * HD + cc;
  s16v8 v0 = *reinterpret_cast<const s16v8*>(src);
  s16v8 v1 = *reinterpret_cast<const s16v8*>(src + 8);
  float4 c0 = *reinterpret_cast<const float4*>(&fc[s * 64 + (cc >> 1)]);
  float4 c1 = *reinterpret_cast<const float4*>(&fc[s * 64 + (cc >> 1) + 4]);
  float4 sv0 = *reinterpret_cast<const float4*>(&fs[s * 64 + (cc >> 1)]);
  float4 sv1 = *reinterpret_cast<const float4*>(&fs[s * 64 + (cc >> 1) + 4]);
  float cA[8] = {c0.x, c0.y, c0.z, c0.w, c1.x, c1.y, c1.z, c1.w};
  float sA[8] = {sv0.x, sv0.y, sv0.z, sv0.w, sv1.x, sv1.y, sv1.z, sv1.w};
  unsigned short e[16];
  #pragma unroll
  for (int k = 0; k < 8; ++k){ e[k] = (unsigned short)v0[k]; e[k + 8] = (unsigned short)v1[k]; }
  #pragma unroll
  for (int pi = 0; pi < 8; ++pi){
    float re = bf2f(e[2 * pi]), im = bf2f(e[2 * pi + 1]);
    Ks[r][cc + 2 * pi]     = f2bf(re * cA[pi] - im * sA[pi]);
    Ks[r][cc + 2 * pi + 1] = f2bf(re * sA[pi] + im * cA[pi]);
  }
  __syncthreads();
  const int l = t & 63;
  #pragma unroll
  for (int p = 0; p < 2; ++p){
    int ds = (t >> 6) * 2 + p;
    s16v8 val = *reinterpret_cast<const s16v8*>(&Ks[l & 31][ds * 16 + (l >> 5) * 8]);
    *reinterpret_cast<s16v8*>(&Kf[(((size_t)bk * 64 + kv32) * 8 + ds) * 512 + (size_t)l * 8]) = val;
  }
}

// ---- V swizzle: QKVb fused (V at col 3072) -> Vf fragment-major ----
__global__ __launch_bounds__(256) void vswz(const unsigned short* __restrict__ QKVb,
                                            unsigned short* __restrict__ Vf){
  __shared__ unsigned short Vs[32][132];
  const int bk = blockIdx.y, kv32 = blockIdx.x;
  const int b = bk >> 3, kvh = bk & 7;
  const int t = threadIdx.x;
  const int r = t >> 3, cc = (t & 7) * 16;
  const int s = kv32 * 32 + r;
  const unsigned short* src = QKVb + (size_t)(b * SEQL + s) * 4096 + 3072 + kvh * HD + cc;
  *reinterpret_cast<s16v8*>(&Vs[r][cc])     = *reinterpret_cast<const s16v8*>(src);
  *reinterpret_cast<s16v8*>(&Vs[r][cc + 8]) = *reinterpret_cast<const s16v8*>(src + 8);
  __syncthreads();
  const int dt = t >> 6, l = t & 63;
  #pragma unroll
  for (int h2 = 0; h2 < 2; ++h2){
    s16v8 val;
    #pragma unroll
    for (int j = 0; j < 8; ++j)
      val[j] = (short)Vs[h2 * 16 + (l >> 5) * 8 + j][dt * 32 + (l & 31)];
    *reinterpret_cast<s16v8*>(&Vf[(((size_t)bk * 64 + kv32) * 8 + dt * 2 + h2) * 512 + (size_t)l * 8]) = val;
  }
}

// ---- flash attention, causal, GQA(2): swapped 32x32, QK pipelined 1 tile ahead ----
// Iteration t: issue kf(t+1)+V(t) loads -> softmax on PREV scores (spa/spb) ->
// QK(t+1) into sna/snb (load wait hidden by softmax, MFMA latency by pack+PV) ->
// pack+PV(t). 2-unrolled to swap score banks without copies.
__global__ __launch_bounds__(64) void fattn8(const unsigned short* __restrict__ Q,
                                             const unsigned short* __restrict__ Kf,
                                             const unsigned short* __restrict__ Vf,
                                             unsigned short* __restrict__ O){
  __shared__ __align__(16) unsigned short Ts[32][40];
  const int id = blockIdx.x;
  const int xcd = id & 7, sub = (id >> 3) & 3;
  const int bh = xcd * 4 + sub;
  const int qi = 63 - (id >> 5);            // heavy q-tiles dispatch first
  const int b = bh >> 4, h = bh & 15, kvh = h >> 1;
  const int bk = b * NKV + kvh;
  const int lane = threadIdx.x;
  const int c = lane & 31, hi = lane >> 5;
  const int q0 = qi * 32;
  const int q = q0 + c;

  bfv8 qf[8];
  {
    const unsigned short* qp = Q + (size_t)(b * SEQL + q) * 4096 + h * HD + hi * 8;
    #pragma unroll
    for (int ds = 0; ds < 8; ++ds) qf[ds] = ld8(qp + ds * 16);
  }

  f32v16 o0 = {}, o1 = {}, o2 = {}, o3 = {};
  float m = -1e30f, l = 0.f;

  const unsigned short* kfb = Kf + ((size_t)bk * 64) * 4096 + (size_t)lane * 8;
  const unsigned short* vfb = Vf + ((size_t)bk * 64) * 4096 + (size_t)lane * 8;

  bfv8 kfA[8];
  #pragma unroll
  for (int ds = 0; ds < 8; ++ds) kfA[ds] = ld8(kfb + ds * 512);

  // prologue: QK(0) into spa/spb
  f32v16 spa = {}, spb = {}, sna = {}, snb = {};
  __builtin_amdgcn_s_setprio(1);
  #pragma unroll
  for (int ds = 0; ds < 4; ++ds){
    spa = mfma32(kfA[ds], qf[ds], spa);
    spb = mfma32(kfA[ds + 4], qf[ds + 4], spb);
  }
  __builtin_amdgcn_s_setprio(0);

#define PACKP(P, PF0, PF1) { \
    unsigned w32[8]; \
    _Pragma("unroll") \
    for (int i = 0; i < 8; ++i){ \
      unsigned short lo_ = __builtin_bit_cast(unsigned short, (__bf16)P[2*i]); \
      unsigned short hb_ = __builtin_bit_cast(unsigned short, (__bf16)P[2*i+1]); \
      w32[i] = (unsigned)lo_ | ((unsigned)hb_ << 16); \
    } \
    i32v2 r0_ = __builtin_amdgcn_permlane32_swap((int)w32[0], (int)w32[2], false, false); \
    i32v2 r1_ = __builtin_amdgcn_permlane32_swap((int)w32[1], (int)w32[3], false, false); \
    i32v2 r2_ = __builtin_amdgcn_permlane32_swap((int)w32[4], (int)w32[6], false, false); \
    i32v2 r3_ = __builtin_amdgcn_permlane32_swap((int)w32[5], (int)w32[7], false, false); \
    u32v4 f0u, f1u; \
    f0u[0] = (unsigned)r0_[0]; f0u[1] = (unsigned)r1_[0]; \
    f0u[2] = (unsigned)r0_[1]; f0u[3] = (unsigned)r1_[1]; \
    f1u[0] = (unsigned)r2_[0]; f1u[1] = (unsigned)r3_[0]; \
    f1u[2] = (unsigned)r2_[1]; f1u[3] = (unsigned)r3_[1]; \
    PF0 = __builtin_bit_cast(bfv8, f0u); \
    PF1 = __builtin_bit_cast(bfv8, f1u); \
  }

#define RESCALE(MX) { \
    if (!__all((MX) - m <= 8.f)){ \
      float mn = fmaxf(m, (MX)); \
      float corr = __builtin_exp2f(m - mn); \
      l *= corr; \
      _Pragma("unroll") \
      for (int r = 0; r < 16; ++r){ o0[r]*=corr; o1[r]*=corr; o2[r]*=corr; o3[r]*=corr; } \
      m = mn; \
    } \
  }

#define PV8(V, PF0, PF1) { \
    __builtin_amdgcn_s_setprio(1); \
    o0 = mfma32(V[0], PF0, o0); o0 = mfma32(V[1], PF1, o0); \
    o1 = mfma32(V[2], PF0, o1); o1 = mfma32(V[3], PF1, o1); \
    o2 = mfma32(V[4], PF0, o2); o2 = mfma32(V[5], PF1, o2); \
    o3 = mfma32(V[6], PF0, o3); o3 = mfma32(V[7], PF1, o3); \
    __builtin_amdgcn_s_setprio(0); \
  }

#define ITER(T, CA, CB, NA, NB) { \
    const bool hn_ = (T) < qi; \
    if (hn_){ \
      const unsigned short* kn_ = kfb + (size_t)((T) + 1) * 4096; \
      _Pragma("unroll") \
      for (int ds = 0; ds < 8; ++ds) kfA[ds] = ld8(kn_ + ds * 512); \
    } \
    const unsigned short* vp_ = vfb + (size_t)(T) * 4096; \
    bfv8 vf[8]; \
    _Pragma("unroll") \
    for (int dv = 0; dv < 8; ++dv) vf[dv] = ld8(vp_ + dv * 512); \
    const bool msk_ = (T) == qi; \
    float t0[16]; \
    _Pragma("unroll") \
    for (int r = 0; r < 16; ++r){ \
      t0[r] = CA[r] + CB[r]; \
      if (msk_ && ((r & 3) + 8 * (r >> 2) + 4 * hi) > c) t0[r] = -3.0e38f; \
    } \
    float m8[8]; \
    _Pragma("unroll") \
    for (int r = 0; r < 8; ++r) m8[r] = fmaxf(t0[2 * r], t0[2 * r + 1]); \
    float m4[4]; \
    _Pragma("unroll") \
    for (int r = 0; r < 4; ++r) m4[r] = fmaxf(m8[2 * r], m8[2 * r + 1]); \
    float mx = fmaxf(fmaxf(m4[0], m4[1]), fmaxf(m4[2], m4[3])); \
    mx = fmaxf(mx, __shfl_xor(mx, 32)); \
    RESCALE(mx) \
    _Pragma("unroll") \
    for (int r = 0; r < 16; ++r) t0[r] = __builtin_exp2f(t0[r] - m); \
    float s8[8]; \
    _Pragma("unroll") \
    for (int r = 0; r < 8; ++r) s8[r] = t0[2 * r] + t0[2 * r + 1]; \
    float s4[4]; \
    _Pragma("unroll") \
    for (int r = 0; r < 4; ++r) s4[r] = s8[2 * r] + s8[2 * r + 1]; \
    float ls = (s4[0] + s4[1]) + (s4[2] + s4[3]); \
    ls += __shfl_xor(ls, 32); \
    l += ls; \
    if (hn_){ \
      NA = {}; NB = {}; \
      __builtin_amdgcn_s_setprio(1); \
      _Pragma("unroll") \
      for (int ds = 0; ds < 4; ++ds){ \
        NA = mfma32(kfA[ds], qf[ds], NA); \
        NB = mfma32(kfA[ds + 4], qf[ds + 4], NB); \
      } \
      __builtin_amdgcn_s_setprio(0); \
    } \
    bfv8 pa0, pa1; \
    PACKP(t0, pa0, pa1) \
    PV8(vf, pa0, pa1) \
  }

  int t = 0;
  for (;;){
    ITER(t, spa, spb, sna, snb)
    if (++t > qi) break;
    ITER(t, sna, snb, spa, spb)
    if (++t > qi) break;
  }
#undef ITER
#undef PACKP
#undef RESCALE
#undef PV8

  const float inv = 1.f / l;
  #define EPI(ODT, DT) \
  { \
    _Pragma("unroll") \
    for (int r = 0; r < 16; ++r) \
      Ts[c][(r & 3) + 8 * (r >> 2) + 4 * hi] = f2bf(ODT[r] * inv); \
    asm volatile("s_waitcnt lgkmcnt(0)" ::: "memory"); \
    _Pragma("unroll") \
    for (int pz = 0; pz < 2; ++pz){ \
      int qr = (lane >> 2) + pz * 16; \
      int dcol = (lane & 3) * 8; \
      s16v8 val = *reinterpret_cast<const s16v8*>(&Ts[qr][dcol]); \
      *reinterpret_cast<s16v8*>(&O[(size_t)(b * SEQL + q0 + qr) * DIMN + h * HD + DT * 32 + dcol]) = val; \
    } \
    asm volatile("s_waitcnt lgkmcnt(0)" ::: "memory"); \
  }
  EPI(o0, 0) EPI(o1, 1) EPI(o2, 2) EPI(o3, 3)
  #undef EPI
}

extern "C" void kernel_launch(void* const* d_in, const int* in_sizes, int n_in,
                              void* d_out, int out_size, void* d_ws, size_t ws_size,
                              hipStream_t stream){
  const float* x  = (const float*)d_in[0];
  const float* fc = (const float*)d_in[1];
  const float* fs = (const float*)d_in[2];
  const float* wq = (const float*)d_in[3];
  const float* wk = (const float*)d_in[4];
  const float* wv = (const float*)d_in[5];
  const float* wo = (const float*)d_in[6];
  float* out = (float*)d_out;
  char* ws = (char*)d_ws;
  unsigned short* xb   = (unsigned short*)(ws);              // 16 MB
  unsigned short* wqkv = (unsigned short*)(ws + 16777216);   // 16 MB fused [4096][2048] weights
  unsigned short* wkb  = (unsigned short*)(ws + 25165824);   //   (wk part)
  unsigned short* wob  = (unsigned short*)(ws + 33554432);   // 8 MB
  unsigned short* QKVb = (unsigned short*)(ws + 41943040);   // 32 MB fused [4096][4096]
  unsigned short* Ab   = (unsigned short*)(ws + 75497472);   // 16 MB
  unsigned short* Kf   = wqkv;                               // reuse weight slot (8 MB)
  unsigned short* Vf   = wkb;                                // reuse weight slot (8 MB)

  const float c1 = 0.08838834764831845f * 1.4426950408889634f;

  dim3 blk(256);
  cvtall<<<dim3(20480), blk, 0, stream>>>(x, wq, wk, wv, wo, xb, wqkv, wob);
  gemm3<<<dim3(256), dim3(512), 0, stream>>>(xb, wqkv, QKVb, 4096, 4096, 2048);
  ropek<<<dim3(16384), blk, 0, stream>>>(QKVb, fc, fs, 2048, 4096, c1);
  kswz<<<dim3(64, 16), blk, 0, stream>>>(QKVb, fc, fs, Kf);
  vswz<<<dim3(64, 16), blk, 0, stream>>>(QKVb, Vf);
  fattn8<<<dim3(2048), dim3(64), 0, stream>>>(QKVb, Kf, Vf, Ab);
  gemm3n<<<dim3(256), dim3(512), 0, stream>>>(Ab, wob, out, 4096, 2048, 2048);
}

// Round 12
// 201.751 us; speedup vs baseline: 1.0983x; 1.0983x over previous
//
#include <hip/hip_runtime.h>
#include <hip/hip_bf16.h>

#define SEQL 2048
#define DIMN 2048
#define NH 16
#define NKV 8
#define HD 128
#define NB 2

typedef float f32v4 __attribute__((ext_vector_type(4)));
typedef float f32v16 __attribute__((ext_vector_type(16)));
typedef __bf16 bfv8 __attribute__((ext_vector_type(8)));
typedef short s16v8 __attribute__((ext_vector_type(8)));
typedef unsigned short u16v4 __attribute__((ext_vector_type(4)));
typedef unsigned int u32v4 __attribute__((ext_vector_type(4)));
typedef int i32v2 __attribute__((ext_vector_type(2)));

__device__ inline unsigned short f2bf(float f){
  union { float f; unsigned u; } v; v.f = f;
  unsigned r = (v.u + 0x7fffu + ((v.u >> 16) & 1u)) >> 16;
  return (unsigned short)r;
}
__device__ inline float bf2f(unsigned short u){
  union { unsigned u; float f; } v; v.u = ((unsigned)u) << 16;
  return v.f;
}
__device__ inline f32v4 mfma16(bfv8 a, bfv8 b, f32v4 c){
  return __builtin_amdgcn_mfma_f32_16x16x32_bf16(a, b, c, 0, 0, 0);
}
__device__ inline f32v16 mfma32(bfv8 a, bfv8 b, f32v16 c){
  return __builtin_amdgcn_mfma_f32_32x32x16_bf16(a, b, c, 0, 0, 0);
}
__device__ inline bfv8 ld8(const unsigned short* p){
  s16v8 v = *reinterpret_cast<const s16v8*>(p);
  return __builtin_bit_cast(bfv8, v);
}
__device__ inline void gload16(const void* g, void* l){
  __builtin_amdgcn_global_load_lds(
      (const __attribute__((address_space(1))) unsigned int*)g,
      (__attribute__((address_space(3))) unsigned int*)l, 16, 0, 0);
}

// ---- fused fp32 -> bf16 convert for all 5 inputs (one dispatch) ----
__global__ __launch_bounds__(256) void cvtall(const float* __restrict__ x,
                                              const float* __restrict__ wq,
                                              const float* __restrict__ wk,
                                              const float* __restrict__ wv,
                                              const float* __restrict__ wo,
                                              unsigned short* __restrict__ xb,
                                              unsigned short* __restrict__ wqkvb,
                                              unsigned short* __restrict__ wob){
  const int bid = blockIdx.x;
  const float* src; unsigned short* dst; int off;
  if (bid < 8192)       { src = x;  dst = xb;              off = bid; }
  else if (bid < 12288) { src = wq; dst = wqkvb;           off = bid - 8192; }
  else if (bid < 14336) { src = wk; dst = wqkvb + 4194304; off = bid - 12288; }
  else if (bid < 16384) { src = wv; dst = wqkvb + 6291456; off = bid - 14336; }
  else                  { src = wo; dst = wob;             off = bid - 16384; }
  const int i = off * 256 + threadIdx.x;
  const float4 v = reinterpret_cast<const float4*>(src)[i];
  u16v4 w; w[0] = f2bf(v.x); w[1] = f2bf(v.y); w[2] = f2bf(v.z); w[3] = f2bf(v.w);
  reinterpret_cast<u16v4*>(dst)[i] = w;
}

// ---- deep-pipelined 256x256 GEMM: C = A * B^T, bf16 out (proven round-7) ----
__global__ __launch_bounds__(512, 2) void gemm3(const unsigned short* __restrict__ A,
                                                const unsigned short* __restrict__ B,
                                                unsigned short* __restrict__ Cp,
                                                int M, int N, int K){
  __shared__ unsigned short lds[65536];   // 4 slots x 16384 elems = 128 KB
  const int tid = threadIdx.x;
  const int lane = tid & 63, w = tid >> 6;
  const int wm = w >> 2, wn = w & 3;
  const int nbx = N >> 8;
  const int nwg = gridDim.x;
  const int cpx = nwg >> 3;
  const int id = blockIdx.x;
  const int swz = (id & 7) * cpx + (id >> 3);   // XCD-affine (nwg % 8 == 0)
  const int bm = (swz / nbx) * 256, bn = (swz % nbx) * 256;
  const int l15 = lane & 15, lg = lane >> 4;
  const int srow = w * 16 + (lane >> 2);
  const int cbg = ((lane & 3) ^ ((lane >> 3) & 3)) * 8;
  const int cbA = (lg ^ ((l15 >> 1) & 3)) * 8;

#define STAGE_A(T) { \
    const int kt_ = (T) * 32; \
    const int sl_ = ((T) & 3) * 16384; \
    const unsigned short* ga_ = &A[(size_t)(bm + srow) * K + kt_ + cbg]; \
    gload16(ga_,                    &lds[sl_ + w * 512]); \
    gload16(ga_ + (size_t)128 * K,  &lds[sl_ + 4096 + w * 512]); \
  }
#define STAGE_B(T) { \
    const int kt_ = (T) * 32; \
    const int sl_ = ((T) & 3) * 16384; \
    const unsigned short* gb_ = &B[(size_t)(bn + srow) * K + kt_ + cbg]; \
    gload16(gb_,                    &lds[sl_ + 8192 + w * 512]); \
    gload16(gb_ + (size_t)128 * K,  &lds[sl_ + 12288 + w * 512]); \
  }

  STAGE_A(0) STAGE_B(0) STAGE_A(1) STAGE_B(1) STAGE_A(2) STAGE_B(2)
  asm volatile("s_waitcnt vmcnt(8)" ::: "memory");
  __builtin_amdgcn_s_barrier();

  f32v4 acc[8][4] = {};
  const int nt = K >> 5;
  for (int t = 0; t < nt; ++t){
    const bool st = (t + 3 < nt);
    const int sl = (t & 3) * 16384;
    bfv8 af[8], bfr[4];
    #pragma unroll
    for (int j = 0; j < 4; ++j)
      bfr[j] = ld8(&lds[sl + 8192 + (wn * 64 + j * 16 + l15) * 32 + cbA]);
    #pragma unroll
    for (int i = 0; i < 4; ++i)
      af[i] = ld8(&lds[sl + (wm * 128 + i * 16 + l15) * 32 + cbA]);
    if (st) STAGE_A(t + 3)
    __builtin_amdgcn_s_barrier();
    __builtin_amdgcn_s_setprio(1);
    #pragma unroll
    for (int i = 0; i < 4; ++i)
      #pragma unroll
      for (int j = 0; j < 4; ++j)
        acc[i][j] = mfma16(af[i], bfr[j], acc[i][j]);
    __builtin_amdgcn_s_setprio(0);
    #pragma unroll
    for (int i = 4; i < 8; ++i)
      af[i] = ld8(&lds[sl + (wm * 128 + i * 16 + l15) * 32 + cbA]);
    if (st) STAGE_B(t + 3)
    __builtin_amdgcn_s_setprio(1);
    #pragma unroll
    for (int i = 4; i < 8; ++i)
      #pragma unroll
      for (int j = 0; j < 4; ++j)
        acc[i][j] = mfma16(af[i], bfr[j], acc[i][j]);
    __builtin_amdgcn_s_setprio(0);
    if (st)                asm volatile("s_waitcnt vmcnt(8)" ::: "memory");
    else if (t == nt - 3)  asm volatile("s_waitcnt vmcnt(4)" ::: "memory");
    else                   asm volatile("s_waitcnt vmcnt(0)" ::: "memory");
    __builtin_amdgcn_s_barrier();
  }
#undef STAGE_A
#undef STAGE_B

  #pragma unroll
  for (int i = 0; i < 8; ++i){
    #pragma unroll
    for (int j = 0; j < 4; ++j){
      const int gr = bm + wm * 128 + i * 16 + lg * 4;
      const int gc = bn + wn * 64 + j * 16 + l15;
      #pragma unroll
      for (int r = 0; r < 4; ++r)
        Cp[(size_t)(gr + r) * N + gc] = f2bf(acc[i][j][r]);
    }
  }
}

// ---- deep-pipelined 256x128 GEMM: C = A * B^T, fp32 out (WO projection) ----
__global__ __launch_bounds__(512, 2) void gemm3n(const unsigned short* __restrict__ A,
                                                 const unsigned short* __restrict__ B,
                                                 float* __restrict__ Cp,
                                                 int M, int N, int K){
  __shared__ unsigned short lds[49152];   // 4 slots x 12288 elems = 96 KB
  const int tid = threadIdx.x;
  const int lane = tid & 63, w = tid >> 6;
  const int wm = w >> 1, wn = w & 1;
  const int nbx = N >> 7;
  const int nwg = gridDim.x;
  const int cpx = nwg >> 3;
  const int id = blockIdx.x;
  const int swz = (id & 7) * cpx + (id >> 3);
  const int bm = (swz / nbx) * 256, bn = (swz % nbx) * 128;
  const int l15 = lane & 15, lg = lane >> 4;
  const int srow = tid >> 2;                       // 0..127
  const int cbg = ((tid & 3) ^ ((tid >> 3) & 3)) * 8;
  const int cbA = (lg ^ ((l15 >> 1) & 3)) * 8;

#define STAGEN(T) { \
    const int kt_ = (T) * 32; \
    const int sl_ = ((T) & 3) * 12288; \
    const unsigned short* ga_ = &A[(size_t)(bm + srow) * K + kt_ + cbg]; \
    gload16(ga_,                    &lds[sl_ + w * 512]); \
    gload16(ga_ + (size_t)128 * K,  &lds[sl_ + 4096 + w * 512]); \
    const unsigned short* gb_ = &B[(size_t)(bn + srow) * K + kt_ + cbg]; \
    gload16(gb_,                    &lds[sl_ + 8192 + w * 512]); \
  }

  STAGEN(0) STAGEN(1) STAGEN(2)
  asm volatile("s_waitcnt vmcnt(6)" ::: "memory");
  __builtin_amdgcn_s_barrier();

  f32v4 acc[4][4] = {};
  const int nt = K >> 5;
  for (int t = 0; t < nt; ++t){
    const bool st = (t + 3 < nt);
    if (st) STAGEN(t + 3)
    const int sl = (t & 3) * 12288;
    bfv8 af[4], bfr[4];
    #pragma unroll
    for (int i = 0; i < 4; ++i)
      af[i] = ld8(&lds[sl + (wm * 64 + i * 16 + l15) * 32 + cbA]);
    #pragma unroll
    for (int j = 0; j < 4; ++j)
      bfr[j] = ld8(&lds[sl + 8192 + (wn * 64 + j * 16 + l15) * 32 + cbA]);
    __builtin_amdgcn_s_setprio(1);
    #pragma unroll
    for (int i = 0; i < 4; ++i)
      #pragma unroll
      for (int j = 0; j < 4; ++j)
        acc[i][j] = mfma16(af[i], bfr[j], acc[i][j]);
    __builtin_amdgcn_s_setprio(0);
    if (st)                asm volatile("s_waitcnt vmcnt(6)" ::: "memory");
    else if (t == nt - 3)  asm volatile("s_waitcnt vmcnt(3)" ::: "memory");
    else                   asm volatile("s_waitcnt vmcnt(0)" ::: "memory");
    __builtin_amdgcn_s_barrier();
  }
#undef STAGEN

  #pragma unroll
  for (int i = 0; i < 4; ++i){
    #pragma unroll
    for (int j = 0; j < 4; ++j){
      const int gr = bm + wm * 64 + i * 16 + lg * 4;
      const int gc = bn + wn * 64 + j * 16 + l15;
      #pragma unroll
      for (int r = 0; r < 4; ++r)
        Cp[(size_t)(gr + r) * N + gc] = acc[i][j][r];
    }
  }
}

// ---- merged K/V swizzle: y<16 -> K (RoPE fused), else V ----
__global__ __launch_bounds__(256) void kvswz(const unsigned short* __restrict__ QKVb,
                                             const float* __restrict__ fc,
                                             const float* __restrict__ fs,
                                             unsigned short* __restrict__ Kf,
                                             unsigned short* __restrict__ Vf){
  __shared__ unsigned short Ts[32][132];
  const int y = blockIdx.y, kv32 = blockIdx.x;
  const int t = threadIdx.x;
  const int r = t >> 3, cc = (t & 7) * 16;
  const int s = kv32 * 32 + r;
  if (y < 16){
    const int bk = y;
    const int b = bk >> 3, kvh = bk & 7;
    const unsigned short* src = QKVb + (size_t)(b * SEQL + s) * 4096 + 2048 + kvh * HD + cc;
    s16v8 v0 = *reinterpret_cast<const s16v8*>(src);
    s16v8 v1 = *reinterpret_cast<const s16v8*>(src + 8);
    float4 c0 = *reinterpret_cast<const float4*>(&fc[s * 64 + (cc >> 1)]);
    float4 c1 = *reinterpret_cast<const float4*>(&fc[s * 64 + (cc >> 1) + 4]);
    float4 sv0 = *reinterpret_cast<const float4*>(&fs[s * 64 + (cc >> 1)]);
    float4 sv1 = *reinterpret_cast<const float4*>(&fs[s * 64 + (cc >> 1) + 4]);
    float cA[8] = {c0.x, c0.y, c0.z, c0.w, c1.x, c1.y, c1.z, c1.w};
    float sA[8] = {sv0.x, sv0.y, sv0.z, sv0.w, sv1.x, sv1.y, sv1.z, sv1.w};
    unsigned short e[16];
    #pragma unroll
    for (int k = 0; k < 8; ++k){ e[k] = (unsigned short)v0[k]; e[k + 8] = (unsigned short)v1[k]; }
    #pragma unroll
    for (int pi = 0; pi < 8; ++pi){
      float re = bf2f(e[2 * pi]), im = bf2f(e[2 * pi + 1]);
      Ts[r][cc + 2 * pi]     = f2bf(re * cA[pi] - im * sA[pi]);
      Ts[r][cc + 2 * pi + 1] = f2bf(re * sA[pi] + im * cA[pi]);
    }
    __syncthreads();
    const int l = t & 63;
    #pragma unroll
    for (int p = 0; p < 2; ++p){
      int ds = (t >> 6) * 2 + p;
      s16v8 val = *reinterpret_cast<const s16v8*>(&Ts[l & 31][ds * 16 + (l >> 5) * 8]);
      *reinterpret_cast<s16v8*>(&Kf[(((size_t)bk * 64 + kv32) * 8 + ds) * 512 + (size_t)l * 8]) = val;
    }
  } else {
    const int bk = y - 16;
    const int b = bk >> 3, kvh = bk & 7;
    const unsigned short* src = QKVb + (size_t)(b * SEQL + s) * 4096 + 3072 + kvh * HD + cc;
    *reinterpret_cast<s16v8*>(&Ts[r][cc])     = *reinterpret_cast<const s16v8*>(src);
    *reinterpret_cast<s16v8*>(&Ts[r][cc + 8]) = *reinterpret_cast<const s16v8*>(src + 8);
    __syncthreads();
    const int dt = t >> 6, l = t & 63;
    #pragma unroll
    for (int h2 = 0; h2 < 2; ++h2){
      s16v8 val;
      #pragma unroll
      for (int j = 0; j < 8; ++j)
        val[j] = (short)Ts[h2 * 16 + (l >> 5) * 8 + j][dt * 32 + (l & 31)];
      *reinterpret_cast<s16v8*>(&Vf[(((size_t)bk * 64 + kv32) * 8 + dt * 2 + h2) * 512 + (size_t)l * 8]) = val;
    }
  }
}

// ---- flash attention, causal, GQA(2): swapped 32x32, fragment-major K/V ----
// Q-RoPE + softmax scale fused into the prologue (Q read raw from QKVb).
__global__ __launch_bounds__(64) void fattn9(const unsigned short* __restrict__ Q,
                                             const unsigned short* __restrict__ Kf,
                                             const unsigned short* __restrict__ Vf,
                                             const float* __restrict__ fc,
                                             const float* __restrict__ fs,
                                             unsigned short* __restrict__ O){
  __shared__ __align__(16) unsigned short Ts[32][40];
  const int id = blockIdx.x;
  const int xcd = id & 7, sub = (id >> 3) & 3;
  const int bh = xcd * 4 + sub;
  const int qi = 63 - (id >> 5);            // heavy q-tiles dispatch first
  const int b = bh >> 4, h = bh & 15, kvh = h >> 1;
  const int bk = b * NKV + kvh;
  const int lane = threadIdx.x;
  const int c = lane & 31, hi = lane >> 5;
  const int q0 = qi * 32;
  const int q = q0 + c;
  const float c1 = 0.08838834764831845f * 1.4426950408889634f;

  // Q fragments with fused RoPE + scale: frag ds holds d = ds*16 + hi*8 + j,
  // rope pairs are (2u,2u+1) within the frag; pair idx = ds*8 + hi*4 + u.
  bfv8 qf[8];
  {
    const unsigned short* qp = Q + (size_t)(b * SEQL + q) * 4096 + h * HD + hi * 8;
    const float* fcp = fc + (size_t)q * 64 + hi * 4;
    const float* fsp = fs + (size_t)q * 64 + hi * 4;
    #pragma unroll
    for (int ds = 0; ds < 8; ++ds){
      s16v8 raw = *reinterpret_cast<const s16v8*>(qp + ds * 16);
      float4 cv = *reinterpret_cast<const float4*>(fcp + ds * 8);
      float4 sv = *reinterpret_cast<const float4*>(fsp + ds * 8);
      float cA[4] = {cv.x, cv.y, cv.z, cv.w};
      float sA[4] = {sv.x, sv.y, sv.z, sv.w};
      bfv8 outf;
      #pragma unroll
      for (int u = 0; u < 4; ++u){
        float re = bf2f((unsigned short)raw[2 * u]);
        float im = bf2f((unsigned short)raw[2 * u + 1]);
        outf[2 * u]     = (__bf16)((re * cA[u] - im * sA[u]) * c1);
        outf[2 * u + 1] = (__bf16)((re * sA[u] + im * cA[u]) * c1);
      }
      qf[ds] = outf;
    }
  }

  f32v16 o0 = {}, o1 = {}, o2 = {}, o3 = {};
  float m = -1e30f, l = 0.f;

  const unsigned short* kfb = Kf + ((size_t)bk * 64) * 4096 + (size_t)lane * 8;
  const unsigned short* vfb = Vf + ((size_t)bk * 64) * 4096 + (size_t)lane * 8;

  bfv8 kf[8];
  #pragma unroll
  for (int ds = 0; ds < 8; ++ds) kf[ds] = ld8(kfb + ds * 512);

#define AITER(MASKED, PREF, IT) { \
    const unsigned short* vp = vfb + (size_t)(IT) * 4096; \
    bfv8 vf[8]; \
    _Pragma("unroll") \
    for (int dv = 0; dv < 8; ++dv) vf[dv] = ld8(vp + dv * 512); \
    f32v16 sa = {}, sb = {}; \
    __builtin_amdgcn_s_setprio(1); \
    _Pragma("unroll") \
    for (int ds = 0; ds < 4; ++ds){ \
      sa = mfma32(kf[ds], qf[ds], sa); \
      sb = mfma32(kf[ds + 4], qf[ds + 4], sb); \
    } \
    __builtin_amdgcn_s_setprio(0); \
    if (PREF){ \
      const unsigned short* kn = kfb + (size_t)((IT) + 1) * 4096; \
      _Pragma("unroll") \
      for (int ds = 0; ds < 8; ++ds) kf[ds] = ld8(kn + ds * 512); \
    } \
    float t[16]; \
    _Pragma("unroll") \
    for (int r = 0; r < 16; ++r){ \
      t[r] = sa[r] + sb[r]; \
      if (MASKED && ((r & 3) + 8 * (r >> 2) + 4 * hi) > c) t[r] = -3.0e38f; \
    } \
    float mx = t[0]; \
    _Pragma("unroll") \
    for (int r = 1; r < 16; ++r) mx = fmaxf(mx, t[r]); \
    mx = fmaxf(mx, __shfl_xor(mx, 32)); \
    if (!__all(mx - m <= 8.f)){ \
      float mn = fmaxf(m, mx); \
      float corr = __builtin_exp2f(m - mn); \
      l *= corr; \
      _Pragma("unroll") \
      for (int r = 0; r < 16; ++r){ o0[r]*=corr; o1[r]*=corr; o2[r]*=corr; o3[r]*=corr; } \
      m = mn; \
    } \
    float p[16], lsum = 0.f; \
    _Pragma("unroll") \
    for (int r = 0; r < 16; ++r){ p[r] = __builtin_exp2f(t[r] - m); lsum += p[r]; } \
    lsum += __shfl_xor(lsum, 32); \
    l += lsum; \
    unsigned w32[8]; \
    _Pragma("unroll") \
    for (int i = 0; i < 8; ++i){ \
      unsigned short lo_ = __builtin_bit_cast(unsigned short, (__bf16)p[2*i]); \
      unsigned short hb_ = __builtin_bit_cast(unsigned short, (__bf16)p[2*i+1]); \
      w32[i] = (unsigned)lo_ | ((unsigned)hb_ << 16); \
    } \
    i32v2 r0_ = __builtin_amdgcn_permlane32_swap((int)w32[0], (int)w32[2], false, false); \
    i32v2 r1_ = __builtin_amdgcn_permlane32_swap((int)w32[1], (int)w32[3], false, false); \
    i32v2 r2_ = __builtin_amdgcn_permlane32_swap((int)w32[4], (int)w32[6], false, false); \
    i32v2 r3_ = __builtin_amdgcn_permlane32_swap((int)w32[5], (int)w32[7], false, false); \
    u32v4 f0u, f1u; \
    f0u[0] = (unsigned)r0_[0]; f0u[1] = (unsigned)r1_[0]; \
    f0u[2] = (unsigned)r0_[1]; f0u[3] = (unsigned)r1_[1]; \
    f1u[0] = (unsigned)r2_[0]; f1u[1] = (unsigned)r3_[0]; \
    f1u[2] = (unsigned)r2_[1]; f1u[3] = (unsigned)r3_[1]; \
    bfv8 pf0 = __builtin_bit_cast(bfv8, f0u); \
    bfv8 pf1 = __builtin_bit_cast(bfv8, f1u); \
    __builtin_amdgcn_s_setprio(1); \
    o0 = mfma32(vf[0], pf0, o0); \
    o0 = mfma32(vf[1], pf1, o0); \
    o1 = mfma32(vf[2], pf0, o1); \
    o1 = mfma32(vf[3], pf1, o1); \
    o2 = mfma32(vf[4], pf0, o2); \
    o2 = mfma32(vf[5], pf1, o2); \
    o3 = mfma32(vf[6], pf0, o3); \
    o3 = mfma32(vf[7], pf1, o3); \
    __builtin_amdgcn_s_setprio(0); \
  }

  for (int it = 0; it < qi; ++it){
    AITER(false, true, it)
  }
  AITER(true, false, qi)
#undef AITER

  const float inv = 1.f / l;
  #define EPI(ODT, DT) \
  { \
    _Pragma("unroll") \
    for (int r = 0; r < 16; ++r) \
      Ts[c][(r & 3) + 8 * (r >> 2) + 4 * hi] = f2bf(ODT[r] * inv); \
    asm volatile("s_waitcnt lgkmcnt(0)" ::: "memory"); \
    _Pragma("unroll") \
    for (int pz = 0; pz < 2; ++pz){ \
      int qr = (lane >> 2) + pz * 16; \
      int dcol = (lane & 3) * 8; \
      s16v8 val = *reinterpret_cast<const s16v8*>(&Ts[qr][dcol]); \
      *reinterpret_cast<s16v8*>(&O[(size_t)(b * SEQL + q0 + qr) * DIMN + h * HD + DT * 32 + dcol]) = val; \
    } \
    asm volatile("s_waitcnt lgkmcnt(0)" ::: "memory"); \
  }
  EPI(o0, 0) EPI(o1, 1) EPI(o2, 2) EPI(o3, 3)
  #undef EPI
}

extern "C" void kernel_launch(void* const* d_in, const int* in_sizes, int n_in,
                              void* d_out, int out_size, void* d_ws, size_t ws_size,
                              hipStream_t stream){
  const float* x  = (const float*)d_in[0];
  const float* fc = (const float*)d_in[1];
  const float* fs = (const float*)d_in[2];
  const float* wq = (const float*)d_in[3];
  const float* wk = (const float*)d_in[4];
  const float* wv = (const float*)d_in[5];
  const float* wo = (const float*)d_in[6];
  float* out = (float*)d_out;
  char* ws = (char*)d_ws;
  unsigned short* xb   = (unsigned short*)(ws);              // 16 MB
  unsigned short* wqkv = (unsigned short*)(ws + 16777216);   // 16 MB fused [4096][2048] weights
  unsigned short* wkb  = (unsigned short*)(ws + 25165824);   //   (wk part)
  unsigned short* wob  = (unsigned short*)(ws + 33554432);   // 8 MB
  unsigned short* QKVb = (unsigned short*)(ws + 41943040);   // 32 MB fused [4096][4096]
  unsigned short* Ab   = (unsigned short*)(ws + 75497472);   // 16 MB
  unsigned short* Kf   = wqkv;                               // reuse weight slot (8 MB)
  unsigned short* Vf   = wkb;                                // reuse weight slot (8 MB)

  dim3 blk(256);
  cvtall<<<dim3(20480), blk, 0, stream>>>(x, wq, wk, wv, wo, xb, wqkv, wob);
  gemm3<<<dim3(256), dim3(512), 0, stream>>>(xb, wqkv, QKVb, 4096, 4096, 2048);
  kvswz<<<dim3(64, 32), blk, 0, stream>>>(QKVb, fc, fs, Kf, Vf);
  fattn9<<<dim3(2048), dim3(64), 0, stream>>>(QKVb, Kf, Vf, fc, fs, Ab);
  gemm3n<<<dim3(256), dim3(512), 0, stream>>>(Ab, wob, out, 4096, 2048, 2048);
}